// Round 7
// baseline (760.840 us; speedup 1.0000x reference)
//
#include <hip/hip_runtime.h>
#include <cmath>
#include <cstdint>

namespace {

constexpr int kLevels = 8;
constexpr uint32_t kT = 1u << 16;
constexpr uint32_t kPrime1 = 2654435761u;
constexpr uint32_t kPrime2 = 805459861u;
constexpr uint32_t kTabEntries = (uint32_t)kLevels * kT;   // 524288

struct LevelParams {
    float scale[kLevels];
    uint32_t res[kLevels];
    uint32_t hashed_mask;
};

__device__ __forceinline__ float bf_lo(uint32_t v) { return __uint_as_float(v << 16); }
__device__ __forceinline__ float bf_hi(uint32_t v) { return __uint_as_float(v & 0xFFFF0000u); }
__device__ __forceinline__ uint32_t bf_pack(float a, float b) {
    return (__float_as_uint(a) >> 16) | (__float_as_uint(b) & 0xFFFF0000u);
}

// ---- repack fp32 table -> bf16x2 (one u32 per entry) into d_ws -----------
__global__ __launch_bounds__(256) void repack_kernel(
    const float2* __restrict__ tb, uint32_t* __restrict__ bt, uint32_t total)
{
    const uint32_t i = blockIdx.x * blockDim.x + threadIdx.x;
    if (i < total) {
        const float2 t = tb[i];
        bt[i] = bf_pack(t.x, t.y);
    }
}

struct Corner {
    uint32_t hx0, hx1, hy0, hy1, hz0, hz1;
    float w00, w10, w01, w11, wz, wz0;
};

__device__ __forceinline__ Corner make_corner(
    float ux, float uy, float uz, float s, bool hashed, uint32_t r)
{
    Corner C;
    const float px = fmaf(ux, s, 0.5f);
    const float py = fmaf(uy, s, 0.5f);
    const float pz = fmaf(uz, s, 0.5f);
    const float fx = floorf(px), fy = floorf(py), fz = floorf(pz);
    const float wx = px - fx, wy = py - fy;
    C.wz = pz - fz;
    C.wz0 = 1.f - C.wz;
    const uint32_t x0 = (uint32_t)fx, y0 = (uint32_t)fy, z0 = (uint32_t)fz;
    if (hashed) {
        C.hx0 = x0;             C.hx1 = x0 + 1u;
        C.hy0 = y0 * kPrime1;   C.hy1 = C.hy0 + kPrime1;
        C.hz0 = z0 * kPrime2;   C.hz1 = C.hz0 + kPrime2;
    } else {
        const uint32_t r2 = r * r;
        C.hx0 = x0;             C.hx1 = x0 + 1u;
        C.hy0 = y0 * r;         C.hy1 = C.hy0 + r;
        C.hz0 = z0 * r2;        C.hz1 = C.hz0 + r2;
    }
    const float wx0 = 1.f - wx, wy0 = 1.f - wy;
    C.w00 = wx0 * wy0;
    C.w10 = wx  * wy0;
    C.w01 = wx0 * wy;
    C.w11 = wx  * wy;
    return C;
}

__device__ __forceinline__ uint32_t corner_idx(const Corner& C, int c, bool hashed) {
    const uint32_t hx = (c & 1) ? C.hx1 : C.hx0;
    const uint32_t hy = (c & 2) ? C.hy1 : C.hy0;
    const uint32_t hz = (c & 4) ? C.hz1 : C.hz0;
    return hashed ? ((hx ^ hy ^ hz) & (kT - 1u)) : (hx + hy + hz);
}

__device__ __forceinline__ float corner_w(const Corner& C, int c) {
    const float wxy = (c & 2) ? ((c & 1) ? C.w11 : C.w01)
                              : ((c & 1) ? C.w10 : C.w00);
    return wxy * ((c & 4) ? C.wz : C.wz0);
}

// ---- fused encode + MLP, 2 points per thread, bf16 table ------------------
// Natural register allocation (NO min-waves hint: rounds 2/3/5 proved any
// forced cap spills 0.3-0.9 GB of scratch, 2-5x slowdown). No LDS (round 6
// proved level-0 LDS staging is a net loss).
__global__ __launch_bounds__(256) void ngp_fused2_kernel(
    const float* __restrict__ uvi,
    const uint32_t* __restrict__ bt,
    const float* __restrict__ W1,
    const float* __restrict__ b1,
    const float* __restrict__ W2,
    const float* __restrict__ b2,
    float* __restrict__ out,
    int n, LevelParams lp)
{
    const int i = blockIdx.x * blockDim.x + threadIdx.x;
    const int pA = 2 * i, pB = 2 * i + 1;
    if (pA >= n) return;
    const bool hasB = (pB < n);

    const float axu = uvi[3 * pA + 0];
    const float ayu = uvi[3 * pA + 1];
    const float azu = uvi[3 * pA + 2];
    float bxu = 0.f, byu = 0.f, bzu = 0.f;
    if (hasB) {
        bxu = uvi[3 * pB + 0];
        byu = uvi[3 * pB + 1];
        bzu = uvi[3 * pB + 2];
    }

    uint32_t pa[kLevels], pb[kLevels];

    #pragma unroll
    for (int l = 0; l < kLevels; ++l) {
        const float s = lp.scale[l];
        const bool hashed = (lp.hashed_mask >> l) & 1u;
        const uint32_t r = lp.res[l];
        const uint32_t base = (uint32_t)l << 16;

        const Corner A = make_corner(axu, ayu, azu, s, hashed, r);
        const Corner B = make_corner(bxu, byu, bzu, s, hashed, r);

        // issue all 16 independent gathers before consuming any
        uint32_t vA[8], vB[8];
        #pragma unroll
        for (int c = 0; c < 8; ++c) vA[c] = bt[base + corner_idx(A, c, hashed)];
        #pragma unroll
        for (int c = 0; c < 8; ++c) vB[c] = bt[base + corner_idx(B, c, hashed)];

        float a0 = 0.f, a1 = 0.f, c0 = 0.f, c1 = 0.f;
        #pragma unroll
        for (int c = 0; c < 8; ++c) {
            const float wA = corner_w(A, c);
            a0 = fmaf(bf_lo(vA[c]), wA, a0);
            a1 = fmaf(bf_hi(vA[c]), wA, a1);
            const float wB = corner_w(B, c);
            c0 = fmaf(bf_lo(vB[c]), wB, c0);
            c1 = fmaf(bf_hi(vB[c]), wB, c1);
        }
        pa[l] = bf_pack(a0, a1);
        pb[l] = bf_pack(c0, c1);
    }

    // unpack both points' features; encode-loop regs are dead here
    float encA[16], encB[16];
    #pragma unroll
    for (int l = 0; l < kLevels; ++l) {
        encA[2 * l + 0] = bf_lo(pa[l]);
        encA[2 * l + 1] = bf_hi(pa[l]);
        encB[2 * l + 0] = bf_lo(pb[l]);
        encB[2 * l + 1] = bf_hi(pb[l]);
    }

    // MLP interleaved over the two points; weights at compile-time indices
    // -> uniform scalar loads shared by both.
    float la = b2[0], lb = la;
    #pragma unroll
    for (int j = 0; j < 64; ++j) {
        float hA = b1[j], hB = hA;
        #pragma unroll
        for (int k = 0; k < 16; ++k) {
            const float w = W1[k * 64 + j];
            hA = fmaf(encA[k], w, hA);
            hB = fmaf(encB[k], w, hB);
        }
        hA = fmaxf(hA, 0.f);
        hB = fmaxf(hB, 0.f);
        const float w2 = W2[j];
        la = fmaf(hA, w2, la);
        lb = fmaf(hB, w2, lb);
    }

    const float sa = 1.f / (1.f + __expf(-la));
    const float sb = 1.f / (1.f + __expf(-lb));
    if (hasB) {
        reinterpret_cast<float2*>(out)[i] = make_float2(sa, sb);
    } else {
        out[pA] = sa;
    }
}

// ---- fallback (ws too small): round-1-style fused, fp32 table ------------
__global__ __launch_bounds__(256) void ngp_fused_kernel(
    const float* __restrict__ uvi,
    const float* __restrict__ table,
    const float* __restrict__ W1,
    const float* __restrict__ b1,
    const float* __restrict__ W2,
    const float* __restrict__ b2,
    float* __restrict__ out,
    int n, LevelParams lp)
{
    const int i = blockIdx.x * blockDim.x + threadIdx.x;
    if (i >= n) return;
    const float ux = uvi[3 * i + 0];
    const float uy = uvi[3 * i + 1];
    const float uz = uvi[3 * i + 2];
    const float2* __restrict__ tb = reinterpret_cast<const float2*>(table);
    float enc[16];
    #pragma unroll
    for (int l = 0; l < kLevels; ++l) {
        const float s = lp.scale[l];
        const bool hashed = (lp.hashed_mask >> l) & 1u;
        const Corner C = make_corner(ux, uy, uz, s, hashed, lp.res[l]);
        const uint32_t base = (uint32_t)l << 16;
        float a0 = 0.f, a1 = 0.f;
        #pragma unroll
        for (int c = 0; c < 8; ++c) {
            const float2 t = tb[base + corner_idx(C, c, hashed)];
            const float w = corner_w(C, c);
            a0 = fmaf(t.x, w, a0);
            a1 = fmaf(t.y, w, a1);
        }
        enc[2 * l + 0] = a0;
        enc[2 * l + 1] = a1;
    }
    float logit = b2[0];
    #pragma unroll
    for (int j = 0; j < 64; ++j) {
        float h = b1[j];
        #pragma unroll
        for (int k = 0; k < 16; ++k)
            h = fmaf(enc[k], W1[k * 64 + j], h);
        h = fmaxf(h, 0.f);
        logit = fmaf(h, W2[j], logit);
    }
    out[i] = 1.f / (1.f + __expf(-logit));
}

} // namespace

extern "C" void kernel_launch(void* const* d_in, const int* in_sizes, int n_in,
                              void* d_out, int out_size, void* d_ws, size_t ws_size,
                              hipStream_t stream)
{
    const float* uvi   = (const float*)d_in[0];
    const float* table = (const float*)d_in[1];
    const float* W1    = (const float*)d_in[2];
    const float* b1    = (const float*)d_in[3];
    const float* W2    = (const float*)d_in[4];
    const float* b2    = (const float*)d_in[5];
    float* out = (float*)d_out;

    const int n = in_sizes[0] / 3;

    // Replicate numpy's double-precision level math exactly.
    LevelParams lp;
    const double B = exp(log(2048.0 / 16.0) / (double)(kLevels - 1));
    uint32_t mask = 0;
    for (int l = 0; l < kLevels; ++l) {
        const double scale_d = 16.0 * pow(B, (double)l) - 1.0;
        const long long res = (long long)ceil(scale_d) + 1;
        lp.scale[l] = (float)scale_d;
        lp.res[l]   = (uint32_t)res;
        if (res * res * res > (long long)kT) mask |= (1u << l);
    }
    lp.hashed_mask = mask;

    const size_t need = (size_t)kTabEntries * 4u;   // 2 MB bf16 table

    if (ws_size >= need) {
        uint32_t* bt = (uint32_t*)d_ws;
        hipLaunchKernelGGL(repack_kernel,
                           dim3((kTabEntries + 255) / 256), dim3(256), 0, stream,
                           reinterpret_cast<const float2*>(table), bt, kTabEntries);
        const int n2 = (n + 1) / 2;
        hipLaunchKernelGGL(ngp_fused2_kernel,
                           dim3((n2 + 255) / 256), dim3(256), 0, stream,
                           uvi, bt, W1, b1, W2, b2, out, n, lp);
    } else {
        hipLaunchKernelGGL(ngp_fused_kernel,
                           dim3((unsigned)((n + 255) / 256)), dim3(256), 0, stream,
                           uvi, table, W1, b1, W2, b2, out, n, lp);
    }
}